// Round 12
// baseline (184.028 us; speedup 1.0000x reference)
//
#include <hip/hip_runtime.h>
#include <hip/hip_bf16.h>

#define C_DIM 256
#define C8 32
#define N_DIM 4096
#define B_DIM 8
#define NSTEP (N_DIM / 32)   // 128 key-steps of 32

using bf16x8 = __attribute__((ext_vector_type(8))) __bf16;
using f32x4  = __attribute__((ext_vector_type(4))) float;
using f32x16 = __attribute__((ext_vector_type(16))) float;
using uint2v = __attribute__((ext_vector_type(2))) unsigned;

#define LOG2E 1.44269504088896f

// Tiled layouts (fragment-major, per batch):
//   Q/K: idx(n,d) = (n>>5)*1024 + (d>>3)*256 + (n&31)*8 + (d&7)    [N*32 elems]
//   V  : idx(c,n) = (n>>4)*4096 + ((n>>3)&1)*2048 + c*8 + (n&7)    [N*C elems]

// ---------------------------------------------------------------------------
// Kernel 0: x[b,c,n] f32  ->  xt[b,n,c] bf16   (LDS tile transpose)
// ---------------------------------------------------------------------------
__global__ __launch_bounds__(256) void k_transpose(
    const float* __restrict__ x, __bf16* __restrict__ xt)
{
    __shared__ float tile[64][65];
    int bid = blockIdx.x;
    int b  = bid >> 8;
    int ct = (bid >> 6) & 3;
    int nt = bid & 63;
    int c0 = ct * 64, n0 = nt * 64;
    int t = threadIdx.x;

    const float* xb = x + (size_t)b * C_DIM * N_DIM;
#pragma unroll
    for (int k = 0; k < 16; k++) {
        int idx = k * 256 + t;
        int i = idx >> 6, j = idx & 63;
        tile[i][j] = xb[(size_t)(c0 + i) * N_DIM + n0 + j];
    }
    __syncthreads();
    __bf16* xtb = xt + (size_t)b * N_DIM * C_DIM;
#pragma unroll
    for (int k = 0; k < 16; k++) {
        int idx = k * 256 + t;
        int nl = idx >> 6, cl = idx & 63;
        xtb[(size_t)(n0 + nl) * C_DIM + c0 + cl] = (__bf16)tile[cl][nl];
    }
}

// ---------------------------------------------------------------------------
// Kernel 1: QKV projection -> TILED outputs. Q pre-scaled by log2(e).
// ---------------------------------------------------------------------------
__global__ __launch_bounds__(256) void k_qkv(
    const float* __restrict__ Wq, const float* __restrict__ bq,
    const float* __restrict__ Wk, const float* __restrict__ bk,
    const float* __restrict__ Wv, const float* __restrict__ bv,
    const __bf16* __restrict__ xt,
    __bf16* __restrict__ Qt, __bf16* __restrict__ Kt, __bf16* __restrict__ Vb)
{
    int bid = blockIdx.x;
    int b   = bid / 320;
    int rem = bid % 320;
    int dt  = rem / 64;
    int nt  = rem % 64;
    int n0  = nt * 64;
    int wid  = threadIdx.x >> 6;
    int lane = threadIdx.x & 63;
    int lg = lane >> 4, li = lane & 15;
    int d0w = dt * 64 + wid * 16;

    int drow = d0w + li;
    const float* wrow;
    if (drow < 32)        wrow = Wq + drow * C_DIM;
    else if (drow < 64)   wrow = Wk + (drow - 32) * C_DIM;
    else                  wrow = Wv + (drow - 64) * C_DIM;

    const __bf16* xtb = xt + (size_t)b * N_DIM * C_DIM;

    f32x4 acc[4] = {};
#pragma unroll
    for (int ks = 0; ks < 8; ks++) {
        int c0 = ks * 32 + lg * 8;
        float4 w0 = *(const float4*)(wrow + c0);
        float4 w1 = *(const float4*)(wrow + c0 + 4);
        bf16x8 af;
        af[0] = (__bf16)w0.x; af[1] = (__bf16)w0.y;
        af[2] = (__bf16)w0.z; af[3] = (__bf16)w0.w;
        af[4] = (__bf16)w1.x; af[5] = (__bf16)w1.y;
        af[6] = (__bf16)w1.z; af[7] = (__bf16)w1.w;
#pragma unroll
        for (int ns = 0; ns < 4; ns++) {
            bf16x8 bfr = *(const bf16x8*)(xtb + (size_t)(n0 + ns * 16 + li) * C_DIM + ks * 32 + lg * 8);
            acc[ns] = __builtin_amdgcn_mfma_f32_16x16x32_bf16(af, bfr, acc[ns], 0, 0, 0);
        }
    }
    __bf16* Qtb = Qt + (size_t)b * (N_DIM * 32);
    __bf16* Ktb = Kt + (size_t)b * (N_DIM * 32);
    __bf16* Vtb = Vb + (size_t)b * (N_DIM * C_DIM);
#pragma unroll
    for (int r = 0; r < 4; r++) {
        int d = d0w + lg * 4 + r;
        float bias = (d < 32) ? bq[d] : (d < 64) ? bk[d - 32] : bv[d - 64];
#pragma unroll
        for (int ns = 0; ns < 4; ns++) {
            int n = n0 + ns * 16 + li;
            float v = acc[ns][r] + bias;
            if (d < 32) {
                int dd = d;
                Qtb[((n >> 5) << 10) + ((dd >> 3) << 8) + ((n & 31) << 3) + (dd & 7)]
                    = (__bf16)(v * LOG2E);
            } else if (d < 64) {
                int dd = d - 32;
                Ktb[((n >> 5) << 10) + ((dd >> 3) << 8) + ((n & 31) << 3) + (dd & 7)]
                    = (__bf16)v;
            } else {
                int c = d - 64;
                Vtb[((n >> 4) << 12) + (((n >> 3) & 1) << 11) + (c << 3) + (n & 7)]
                    = (__bf16)v;
            }
        }
    }
}

// ---------------------------------------------------------------------------
// helpers (numerics verified R7-R11: absmax matched)
// ---------------------------------------------------------------------------
static __device__ __forceinline__ unsigned pack2(float a, float b) {
    union { __bf16 h[2]; unsigned u; } c;
    c.h[0] = (__bf16)a; c.h[1] = (__bf16)b; return c.u;
}
static __device__ __forceinline__ bf16x8 mkfrag(unsigned d0, unsigned d1, unsigned d2, unsigned d3) {
    union { unsigned u[4]; bf16x8 v; } r;
    r.u[0] = d0; r.u[1] = d1; r.u[2] = d2; r.u[3] = d3; return r.v;
}
static __device__ __forceinline__ uint2v plswap(unsigned a, unsigned b) {
#if __has_builtin(__builtin_amdgcn_permlane32_swap)
    return __builtin_amdgcn_permlane32_swap(a, b, false, false);
#else
    unsigned ax = (unsigned)__shfl_xor((int)a, 32);
    unsigned bx = (unsigned)__shfl_xor((int)b, 32);
    int hi = (threadIdx.x >> 5) & 1;
    uint2v r;
    r.x = hi ? bx : a;
    r.y = hi ? b  : ax;
    return r;
#endif
}
// S~ (K·Q^T) 32x32 C/D block -> exp2 (no shift: cancels in O/l)
// -> two PV B-fragments (16-key slices) + l partials.
static __device__ __forceinline__ void soft_pack(
    const f32x16& s, float& l, bf16x8& f0, bf16x8& f1)
{
    float p[16];
#pragma unroll
    for (int r = 0; r < 16; r++) p[r] = __builtin_amdgcn_exp2f(s[r]);
    float lp = 0.f;
#pragma unroll
    for (int r = 0; r < 16; r++) lp += p[r];
    l += lp;
    unsigned a0 = pack2(p[0],  p[1]),  b0 = pack2(p[2],  p[3]);
    unsigned a1 = pack2(p[4],  p[5]),  b1 = pack2(p[6],  p[7]);
    unsigned a2 = pack2(p[8],  p[9]),  b2 = pack2(p[10], p[11]);
    unsigned a3 = pack2(p[12], p[13]), b3 = pack2(p[14], p[15]);
    uint2v rA0 = plswap(a0, a1), rB0 = plswap(b0, b1);
    uint2v rA1 = plswap(a2, a3), rB1 = plswap(b2, b3);
    f0 = mkfrag(rA0.x, rB0.x, rA0.y, rB0.y);   // keys 0..15
    f1 = mkfrag(rA1.x, rB1.x, rA1.y, rB1.y);   // keys 16..31
}

// ---------------------------------------------------------------------------
// Kernel 2: barrier-free flash attention, 2 waves/SIMD for MFMA/VALU overlap.
// Wave = 32 queries x 128 channels x 4096 keys. 2048 waves = 2/SIMD
// (512 blocks): each wave's softpack VALU + load stalls hide under the
// co-wave's MFMA backlog (2x QK + 2x softmax redundancy is the price).
// Same tiled operands, 1-step software pipeline, fused epilogue.
// ---------------------------------------------------------------------------
__global__ __launch_bounds__(256, 2) void k_attn(
    const __bf16* __restrict__ Qt, const __bf16* __restrict__ Kt,
    const __bf16* __restrict__ Vb, const float* __restrict__ x,
    const float* __restrict__ gamma, float* __restrict__ out)
{
    int bid = blockIdx.x;            // 512 blocks, 2 per CU
    int b   = bid & 7;               // batch -> XCD affinity (K/V fit 4MB L2)
    int cs  = (bid >> 3) & 1;        // channel half
    int qg  = bid >> 4;              // 0..31 : group of 4 query-tiles
    int wid = threadIdx.x >> 6;
    int li  = threadIdx.x & 31;
    int hi  = (threadIdx.x >> 5) & 1;
    int n0q = (qg * 4 + wid) * 32;
    int c0  = cs * 128;

    const __bf16* Qtb = Qt + (size_t)b * (N_DIM * 32);
    const __bf16* Ktb = Kt + (size_t)b * (N_DIM * 32);
    const __bf16* Vtb = Vb + (size_t)b * (N_DIM * C_DIM);

    const __bf16* Qlp = Qtb + ((n0q >> 5) << 10) + (hi << 8) + (li << 3);
    bf16x8 qf0 = *(const bf16x8*)(Qlp);        // d 0-15
    bf16x8 qf1 = *(const bf16x8*)(Qlp + 512);  // d 16-31

    const __bf16* Klp = Ktb + (hi << 8) + (li << 3);
    const __bf16* Vlp = Vtb + (hi << 11) + ((c0 + li) << 3);

    f32x16 acc0 = {}, acc1 = {}, acc2 = {}, acc3 = {};
    float l0 = 0.f;

    bf16x8 kA0, kA1, kB0, kB1;
    bf16x8 vA[8], vB[8];
    bf16x8 pA0, pA1, pB0, pB1;

#define KLOAD(D0, D1, S)                                                       \
    { const __bf16* Kn = Klp + ((size_t)(S) << 10);                            \
      D0 = *(const bf16x8*)(Kn); D1 = *(const bf16x8*)(Kn + 512); }

    // frag order: [ct*2 + ks]; addr = step<<13 + ks*4096 + ct*256
#define VLOAD(DST, S)                                                          \
    { const __bf16* Vn = Vlp + ((size_t)(S) << 13);                            \
      _Pragma("unroll")                                                        \
      for (int ct = 0; ct < 4; ct++) {                                         \
          DST[ct * 2 + 0] = *(const bf16x8*)(Vn + ct * 256);                   \
          DST[ct * 2 + 1] = *(const bf16x8*)(Vn + 4096 + ct * 256);            \
      } }

#define PVALL(V, P0, P1)                                                       \
    acc0 = __builtin_amdgcn_mfma_f32_32x32x16_bf16(V[0], P0, acc0, 0, 0, 0);   \
    acc0 = __builtin_amdgcn_mfma_f32_32x32x16_bf16(V[1], P1, acc0, 0, 0, 0);   \
    acc1 = __builtin_amdgcn_mfma_f32_32x32x16_bf16(V[2], P0, acc1, 0, 0, 0);   \
    acc1 = __builtin_amdgcn_mfma_f32_32x32x16_bf16(V[3], P1, acc1, 0, 0, 0);   \
    acc2 = __builtin_amdgcn_mfma_f32_32x32x16_bf16(V[4], P0, acc2, 0, 0, 0);   \
    acc2 = __builtin_amdgcn_mfma_f32_32x32x16_bf16(V[5], P1, acc2, 0, 0, 0);   \
    acc3 = __builtin_amdgcn_mfma_f32_32x32x16_bf16(V[6], P0, acc3, 0, 0, 0);   \
    acc3 = __builtin_amdgcn_mfma_f32_32x32x16_bf16(V[7], P1, acc3, 0, 0, 0);

    // BODY(I): load K(KS)->KL, V(I+1)->VL; s=QK(I+1) from KU; PV(I) from
    // VU/PU (covers s latency); softpack(I+1)->PD (VALU under MFMA backlog).
#define BODY(I, KL0, KL1, VL, KU0, KU1, PD0, PD1, VU, PU0, PU1, KS)            \
    {                                                                          \
        KLOAD(KL0, KL1, KS)                                                    \
        VLOAD(VL, (I) + 1)                                                     \
        f32x16 z = {};                                                         \
        f32x16 s = __builtin_amdgcn_mfma_f32_32x32x16_bf16(KU0, qf0, z, 0, 0, 0); \
        s = __builtin_amdgcn_mfma_f32_32x32x16_bf16(KU1, qf1, s, 0, 0, 0);     \
        PVALL(VU, PU0, PU1)                                                    \
        soft_pack(s, l0, PD0, PD1);                                            \
    }

    // prologue: K(0),K(1),V(0); s(0); softpack(0)->pA
    KLOAD(kA0, kA1, 0)
    KLOAD(kB0, kB1, 1)
    VLOAD(vA, 0)
    {
        f32x16 z = {};
        f32x16 s = __builtin_amdgcn_mfma_f32_32x32x16_bf16(kA0, qf0, z, 0, 0, 0);
        s = __builtin_amdgcn_mfma_f32_32x32x16_bf16(kA1, qf1, s, 0, 0, 0);
        soft_pack(s, l0, pA0, pA1);
    }

    for (int i = 0; i < 126; i += 2) {
        BODY(i,     kA0, kA1, vB, kB0, kB1, pB0, pB1, vA, pA0, pA1, i + 2)
        BODY(i + 1, kB0, kB1, vA, kA0, kA1, pA0, pA1, vB, pB0, pB1, i + 3)
    }
    // i = 126: K reload of 127 (harmless), V(127), QK(127), PV(126)
    BODY(126, kA0, kA1, vB, kB0, kB1, pB0, pB1, vA, pA0, pA1, 127)
    // tail: PV(127)
    PVALL(vB, pB0, pB1)

#undef BODY
#undef PVALL
#undef VLOAD
#undef KLOAD

    // ---- epilogue: l reduce across hi halves, fused gamma/l + residual
    float lv = l0 + __shfl_xor(l0, 32);
    float linv = gamma[0] / lv;

#define STORE_ACC(A, G)                                                        \
    _Pragma("unroll")                                                          \
    for (int rg = 0; rg < 16; rg++) {                                          \
        int row = (rg & 3) + 8 * (rg >> 2) + 4 * hi;                           \
        size_t idx = ((size_t)b * C_DIM + (c0 + (G) * 32 + row)) * N_DIM       \
                     + (n0q + li);                                             \
        out[idx] = A[rg] * linv + x[idx];                                      \
    }
    STORE_ACC(acc0, 0)
    STORE_ACC(acc1, 1)
    STORE_ACC(acc2, 2)
    STORE_ACC(acc3, 3)
#undef STORE_ACC
}

// ---------------------------------------------------------------------------
extern "C" void kernel_launch(void* const* d_in, const int* in_sizes, int n_in,
                              void* d_out, int out_size, void* d_ws, size_t ws_size,
                              hipStream_t stream)
{
    const float* x     = (const float*)d_in[0];
    const float* Wq    = (const float*)d_in[1];
    const float* bq    = (const float*)d_in[2];
    const float* Wk    = (const float*)d_in[3];
    const float* bk    = (const float*)d_in[4];
    const float* Wv    = (const float*)d_in[5];
    const float* bv    = (const float*)d_in[6];
    const float* gamma = (const float*)d_in[7];
    float* out = (float*)d_out;

    char* ws = (char*)d_ws;
    const size_t MB = 1024 * 1024;
    __bf16* xt = (__bf16*)ws;                      // 16 MiB
    __bf16* Qt = (__bf16*)(ws + 16 * MB);          //  2 MiB (tiled)
    __bf16* Kt = (__bf16*)(ws + 18 * MB);          //  2 MiB (tiled)
    __bf16* Vb = (__bf16*)(ws + 20 * MB);          // 16 MiB (tiled)

    k_transpose<<<2048, 256, 0, stream>>>(x, xt);
    k_qkv<<<2560, 256, 0, stream>>>(Wq, bq, Wk, bk, Wv, bv, xt, Qt, Kt, Vb);
    k_attn<<<512, 256, 0, stream>>>(Qt, Kt, Vb, x, gamma, out);
}

// Round 13
// 167.215 us; speedup vs baseline: 1.1006x; 1.1006x over previous
//
#include <hip/hip_runtime.h>
#include <hip/hip_bf16.h>

#define C_DIM 256
#define C8 32
#define N_DIM 4096
#define B_DIM 8
#define KSTEPS 64    // 64 steps x 32 keys = 2048 keys per wave (key half)

using bf16x8 = __attribute__((ext_vector_type(8))) __bf16;
using f32x4  = __attribute__((ext_vector_type(4))) float;
using f32x16 = __attribute__((ext_vector_type(16))) float;
using uint2v = __attribute__((ext_vector_type(2))) unsigned;

#define LOG2E 1.44269504088896f

// Tiled layouts (fragment-major, per batch):
//   Q/K: idx(n,d) = (n>>5)*1024 + (d>>3)*256 + (n&31)*8 + (d&7)    [N*32 elems]
//   V  : idx(c,n) = (n>>4)*4096 + ((n>>3)&1)*2048 + c*8 + (n&7)    [N*C elems]

// ---------------------------------------------------------------------------
// Kernel 0: x[b,c,n] f32  ->  xt[b,n,c] bf16   (LDS tile transpose)
// ---------------------------------------------------------------------------
__global__ __launch_bounds__(256) void k_transpose(
    const float* __restrict__ x, __bf16* __restrict__ xt)
{
    __shared__ float tile[64][65];
    int bid = blockIdx.x;
    int b  = bid >> 8;
    int ct = (bid >> 6) & 3;
    int nt = bid & 63;
    int c0 = ct * 64, n0 = nt * 64;
    int t = threadIdx.x;

    const float* xb = x + (size_t)b * C_DIM * N_DIM;
#pragma unroll
    for (int k = 0; k < 16; k++) {
        int idx = k * 256 + t;
        int i = idx >> 6, j = idx & 63;
        tile[i][j] = xb[(size_t)(c0 + i) * N_DIM + n0 + j];
    }
    __syncthreads();
    __bf16* xtb = xt + (size_t)b * N_DIM * C_DIM;
#pragma unroll
    for (int k = 0; k < 16; k++) {
        int idx = k * 256 + t;
        int nl = idx >> 6, cl = idx & 63;
        xtb[(size_t)(n0 + nl) * C_DIM + c0 + cl] = (__bf16)tile[cl][nl];
    }
}

// ---------------------------------------------------------------------------
// Kernel 1: QKV projection -> TILED outputs. Q pre-scaled by log2(e).
// ---------------------------------------------------------------------------
__global__ __launch_bounds__(256) void k_qkv(
    const float* __restrict__ Wq, const float* __restrict__ bq,
    const float* __restrict__ Wk, const float* __restrict__ bk,
    const float* __restrict__ Wv, const float* __restrict__ bv,
    const __bf16* __restrict__ xt,
    __bf16* __restrict__ Qt, __bf16* __restrict__ Kt, __bf16* __restrict__ Vb)
{
    int bid = blockIdx.x;
    int b   = bid / 320;
    int rem = bid % 320;
    int dt  = rem / 64;
    int nt  = rem % 64;
    int n0  = nt * 64;
    int wid  = threadIdx.x >> 6;
    int lane = threadIdx.x & 63;
    int lg = lane >> 4, li = lane & 15;
    int d0w = dt * 64 + wid * 16;

    int drow = d0w + li;
    const float* wrow;
    if (drow < 32)        wrow = Wq + drow * C_DIM;
    else if (drow < 64)   wrow = Wk + (drow - 32) * C_DIM;
    else                  wrow = Wv + (drow - 64) * C_DIM;

    const __bf16* xtb = xt + (size_t)b * N_DIM * C_DIM;

    f32x4 acc[4] = {};
#pragma unroll
    for (int ks = 0; ks < 8; ks++) {
        int c0 = ks * 32 + lg * 8;
        float4 w0 = *(const float4*)(wrow + c0);
        float4 w1 = *(const float4*)(wrow + c0 + 4);
        bf16x8 af;
        af[0] = (__bf16)w0.x; af[1] = (__bf16)w0.y;
        af[2] = (__bf16)w0.z; af[3] = (__bf16)w0.w;
        af[4] = (__bf16)w1.x; af[5] = (__bf16)w1.y;
        af[6] = (__bf16)w1.z; af[7] = (__bf16)w1.w;
#pragma unroll
        for (int ns = 0; ns < 4; ns++) {
            bf16x8 bfr = *(const bf16x8*)(xtb + (size_t)(n0 + ns * 16 + li) * C_DIM + ks * 32 + lg * 8);
            acc[ns] = __builtin_amdgcn_mfma_f32_16x16x32_bf16(af, bfr, acc[ns], 0, 0, 0);
        }
    }
    __bf16* Qtb = Qt + (size_t)b * (N_DIM * 32);
    __bf16* Ktb = Kt + (size_t)b * (N_DIM * 32);
    __bf16* Vtb = Vb + (size_t)b * (N_DIM * C_DIM);
#pragma unroll
    for (int r = 0; r < 4; r++) {
        int d = d0w + lg * 4 + r;
        float bias = (d < 32) ? bq[d] : (d < 64) ? bk[d - 32] : bv[d - 64];
#pragma unroll
        for (int ns = 0; ns < 4; ns++) {
            int n = n0 + ns * 16 + li;
            float v = acc[ns][r] + bias;
            if (d < 32) {
                int dd = d;
                Qtb[((n >> 5) << 10) + ((dd >> 3) << 8) + ((n & 31) << 3) + (dd & 7)]
                    = (__bf16)(v * LOG2E);
            } else if (d < 64) {
                int dd = d - 32;
                Ktb[((n >> 5) << 10) + ((dd >> 3) << 8) + ((n & 31) << 3) + (dd & 7)]
                    = (__bf16)v;
            } else {
                int c = d - 64;
                Vtb[((n >> 4) << 12) + (((n >> 3) & 1) << 11) + (c << 3) + (n & 7)]
                    = (__bf16)v;
            }
        }
    }
}

// ---------------------------------------------------------------------------
// helpers (numerics verified R7-R12: absmax matched)
// ---------------------------------------------------------------------------
static __device__ __forceinline__ unsigned pack2(float a, float b) {
    union { __bf16 h[2]; unsigned u; } c;
    c.h[0] = (__bf16)a; c.h[1] = (__bf16)b; return c.u;
}
static __device__ __forceinline__ bf16x8 mkfrag(unsigned d0, unsigned d1, unsigned d2, unsigned d3) {
    union { unsigned u[4]; bf16x8 v; } r;
    r.u[0] = d0; r.u[1] = d1; r.u[2] = d2; r.u[3] = d3; return r.v;
}
static __device__ __forceinline__ uint2v plswap(unsigned a, unsigned b) {
#if __has_builtin(__builtin_amdgcn_permlane32_swap)
    return __builtin_amdgcn_permlane32_swap(a, b, false, false);
#else
    unsigned ax = (unsigned)__shfl_xor((int)a, 32);
    unsigned bx = (unsigned)__shfl_xor((int)b, 32);
    int hi = (threadIdx.x >> 5) & 1;
    uint2v r;
    r.x = hi ? bx : a;
    r.y = hi ? b  : ax;
    return r;
#endif
}
// S~ (K·Q^T) 32x32 C/D block -> exp2 (no shift: cancels in O/l)
// -> two PV B-fragments (16-key slices) + l partials.
static __device__ __forceinline__ void soft_pack(
    const f32x16& s, float& l, bf16x8& f0, bf16x8& f1)
{
    float p[16];
#pragma unroll
    for (int r = 0; r < 16; r++) p[r] = __builtin_amdgcn_exp2f(s[r]);
    float lp = 0.f;
#pragma unroll
    for (int r = 0; r < 16; r++) lp += p[r];
    l += lp;
    unsigned a0 = pack2(p[0],  p[1]),  b0 = pack2(p[2],  p[3]);
    unsigned a1 = pack2(p[4],  p[5]),  b1 = pack2(p[6],  p[7]);
    unsigned a2 = pack2(p[8],  p[9]),  b2 = pack2(p[10], p[11]);
    unsigned a3 = pack2(p[12], p[13]), b3 = pack2(p[14], p[15]);
    uint2v rA0 = plswap(a0, a1), rB0 = plswap(b0, b1);
    uint2v rA1 = plswap(a2, a3), rB1 = plswap(b2, b3);
    f0 = mkfrag(rA0.x, rB0.x, rA0.y, rB0.y);   // keys 0..15
    f1 = mkfrag(rA1.x, rB1.x, rA1.y, rB1.y);   // keys 16..31
}

// ---------------------------------------------------------------------------
// Kernel 2: barrier-free main loop, key-split across co-resident waves.
// Wave = 32 queries x 256 channels x 2048 keys (key half ks). ZERO softmax /
// QK redundancy AND 2 waves/SIMD TLP: the co-wave's MFMA backlog hides this
// wave's softpack VALU and V loads. Block = 4 waves = 2 query-tiles x 2 key
// halves; merge is a pure SUM (no-max softmax) via bf16 LDS + ONE barrier.
// ---------------------------------------------------------------------------
__global__ __launch_bounds__(256, 2) void k_attn(
    const __bf16* __restrict__ Qt, const __bf16* __restrict__ Kt,
    const __bf16* __restrict__ Vb, const float* __restrict__ x,
    const float* __restrict__ gamma, float* __restrict__ out)
{
    __shared__ __bf16 accs[2][C_DIM][32];   // 32 KiB: ks=1 partial O
    __shared__ float  lbuf[2][32];

    int bid = blockIdx.x;            // 512 blocks, 2 per CU
    int b   = bid & 7;               // batch -> XCD affinity (K/V in 4MB L2)
    int qp  = bid >> 3;              // 0..63 : query-tile pair
    int wid  = threadIdx.x >> 6;
    int qsel = wid >> 1;             // which of the 2 query-tiles
    int ks   = wid & 1;              // key half
    int li  = threadIdx.x & 31;
    int hi  = (threadIdx.x >> 5) & 1;
    int n0q = (qp * 2 + qsel) * 32;

    const __bf16* Qtb = Qt + (size_t)b * (N_DIM * 32);
    const __bf16* Ktb = Kt + (size_t)b * (N_DIM * 32);
    const __bf16* Vtb = Vb + (size_t)b * (N_DIM * C_DIM);

    const __bf16* Qlp = Qtb + ((n0q >> 5) << 10) + (hi << 8) + (li << 3);
    bf16x8 qf0 = *(const bf16x8*)(Qlp);        // d 0-15
    bf16x8 qf1 = *(const bf16x8*)(Qlp + 512);  // d 16-31

    // key-half base: step s of this wave = global step ks*64 + s
    const __bf16* Klp = Ktb + ((size_t)(ks * KSTEPS) << 10) + (hi << 8) + (li << 3);
    const __bf16* Vlp = Vtb + ((size_t)(ks * KSTEPS) << 13) + (hi << 11) + (li << 3);

    f32x16 acc0 = {}, acc1 = {}, acc2 = {}, acc3 = {};
    f32x16 acc4 = {}, acc5 = {}, acc6 = {}, acc7 = {};
    float l0 = 0.f;

    bf16x8 kA0, kA1, kB0, kB1;

#define KLOAD(D0, D1, S)                                                       \
    { const __bf16* Kn = Klp + ((size_t)(S) << 10);                            \
      D0 = *(const bf16x8*)(Kn); D1 = *(const bf16x8*)(Kn + 512); }

    // STEP(I): s = QK(I) from KU; prefetch K(KS2)->KL; V in 2 chunks of 8
    // frags (live V <= ~40 regs); PV interleaved with the 2nd chunk's loads.
#define STEP(KU0, KU1, KL0, KL1, KS2, I)                                       \
    {                                                                          \
        f32x16 z = {};                                                         \
        f32x16 s = __builtin_amdgcn_mfma_f32_32x32x16_bf16(KU0, qf0, z, 0, 0, 0); \
        s = __builtin_amdgcn_mfma_f32_32x32x16_bf16(KU1, qf1, s, 0, 0, 0);     \
        KLOAD(KL0, KL1, KS2)                                                   \
        const __bf16* Vn = Vlp + ((size_t)(I) << 13);                          \
        bf16x8 v0 = *(const bf16x8*)(Vn);                                      \
        bf16x8 v1 = *(const bf16x8*)(Vn + 4096);                               \
        bf16x8 v2 = *(const bf16x8*)(Vn + 256);                                \
        bf16x8 v3 = *(const bf16x8*)(Vn + 4096 + 256);                         \
        bf16x8 v4 = *(const bf16x8*)(Vn + 512);                                \
        bf16x8 v5 = *(const bf16x8*)(Vn + 4096 + 512);                         \
        bf16x8 v6 = *(const bf16x8*)(Vn + 768);                                \
        bf16x8 v7 = *(const bf16x8*)(Vn + 4096 + 768);                         \
        bf16x8 p0, p1;                                                         \
        soft_pack(s, l0, p0, p1);                                              \
        acc0 = __builtin_amdgcn_mfma_f32_32x32x16_bf16(v0, p0, acc0, 0, 0, 0); \
        acc0 = __builtin_amdgcn_mfma_f32_32x32x16_bf16(v1, p1, acc0, 0, 0, 0); \
        bf16x8 w0 = *(const bf16x8*)(Vn + 1024);                               \
        bf16x8 w1 = *(const bf16x8*)(Vn + 4096 + 1024);                        \
        acc1 = __builtin_amdgcn_mfma_f32_32x32x16_bf16(v2, p0, acc1, 0, 0, 0); \
        acc1 = __builtin_amdgcn_mfma_f32_32x32x16_bf16(v3, p1, acc1, 0, 0, 0); \
        bf16x8 w2 = *(const bf16x8*)(Vn + 1280);                               \
        bf16x8 w3 = *(const bf16x8*)(Vn + 4096 + 1280);                        \
        acc2 = __builtin_amdgcn_mfma_f32_32x32x16_bf16(v4, p0, acc2, 0, 0, 0); \
        acc2 = __builtin_amdgcn_mfma_f32_32x32x16_bf16(v5, p1, acc2, 0, 0, 0); \
        bf16x8 w4 = *(const bf16x8*)(Vn + 1536);                               \
        bf16x8 w5 = *(const bf16x8*)(Vn + 4096 + 1536);                        \
        acc3 = __builtin_amdgcn_mfma_f32_32x32x16_bf16(v6, p0, acc3, 0, 0, 0); \
        acc3 = __builtin_amdgcn_mfma_f32_32x32x16_bf16(v7, p1, acc3, 0, 0, 0); \
        bf16x8 w6 = *(const bf16x8*)(Vn + 1792);                               \
        bf16x8 w7 = *(const bf16x8*)(Vn + 4096 + 1792);                        \
        acc4 = __builtin_amdgcn_mfma_f32_32x32x16_bf16(w0, p0, acc4, 0, 0, 0); \
        acc4 = __builtin_amdgcn_mfma_f32_32x32x16_bf16(w1, p1, acc4, 0, 0, 0); \
        acc5 = __builtin_amdgcn_mfma_f32_32x32x16_bf16(w2, p0, acc5, 0, 0, 0); \
        acc5 = __builtin_amdgcn_mfma_f32_32x32x16_bf16(w3, p1, acc5, 0, 0, 0); \
        acc6 = __builtin_amdgcn_mfma_f32_32x32x16_bf16(w4, p0, acc6, 0, 0, 0); \
        acc6 = __builtin_amdgcn_mfma_f32_32x32x16_bf16(w5, p1, acc6, 0, 0, 0); \
        acc7 = __builtin_amdgcn_mfma_f32_32x32x16_bf16(w6, p0, acc7, 0, 0, 0); \
        acc7 = __builtin_amdgcn_mfma_f32_32x32x16_bf16(w7, p1, acc7, 0, 0, 0); \
    }

    // prologue: K(0), K(1)
    KLOAD(kA0, kA1, 0)
    KLOAD(kB0, kB1, 1)

    for (int i = 0; i < KSTEPS - 2; i += 2) {
        STEP(kA0, kA1, kA0, kA1, i + 2, i)
        STEP(kB0, kB1, kB0, kB1, i + 3, i + 1)
    }
    STEP(kA0, kA1, kA0, kA1, KSTEPS - 1, KSTEPS - 2)   // K reload: harmless
    STEP(kB0, kB1, kB0, kB1, KSTEPS - 1, KSTEPS - 1)

#undef STEP
#undef KLOAD

    // ---- merge the two key halves: ks=1 -> LDS (bf16 partials + l), barrier,
    //      ks=0 adds and runs the fused epilogue.
    float lv = l0 + __shfl_xor(l0, 32);   // per-lane query li's partial sum

    if (ks == 1) {
        if (hi == 0) lbuf[qsel][li] = lv;
#define SPILL_ACC(A, G)                                                        \
        _Pragma("unroll")                                                      \
        for (int rg = 0; rg < 16; rg++) {                                      \
            int row = (rg & 3) + 8 * (rg >> 2) + 4 * hi;                       \
            accs[qsel][(G) * 32 + row][li] = (__bf16)A[rg];                    \
        }
        SPILL_ACC(acc0, 0) SPILL_ACC(acc1, 1) SPILL_ACC(acc2, 2) SPILL_ACC(acc3, 3)
        SPILL_ACC(acc4, 4) SPILL_ACC(acc5, 5) SPILL_ACC(acc6, 6) SPILL_ACC(acc7, 7)
#undef SPILL_ACC
    }
    __syncthreads();
    if (ks == 0) {
        float lt = lv + lbuf[qsel][li];
        float linv = gamma[0] / lt;
#define STORE_ACC(A, G)                                                        \
        _Pragma("unroll")                                                      \
        for (int rg = 0; rg < 16; rg++) {                                      \
            int row = (rg & 3) + 8 * (rg >> 2) + 4 * hi;                       \
            int c = (G) * 32 + row;                                            \
            size_t idx = ((size_t)b * C_DIM + c) * N_DIM + (n0q + li);         \
            float o = A[rg] + (float)accs[qsel][c][li];                        \
            out[idx] = o * linv + x[idx];                                      \
        }
        STORE_ACC(acc0, 0) STORE_ACC(acc1, 1) STORE_ACC(acc2, 2) STORE_ACC(acc3, 3)
        STORE_ACC(acc4, 4) STORE_ACC(acc5, 5) STORE_ACC(acc6, 6) STORE_ACC(acc7, 7)
#undef STORE_ACC
    }
}

// ---------------------------------------------------------------------------
extern "C" void kernel_launch(void* const* d_in, const int* in_sizes, int n_in,
                              void* d_out, int out_size, void* d_ws, size_t ws_size,
                              hipStream_t stream)
{
    const float* x     = (const float*)d_in[0];
    const float* Wq    = (const float*)d_in[1];
    const float* bq    = (const float*)d_in[2];
    const float* Wk    = (const float*)d_in[3];
    const float* bk    = (const float*)d_in[4];
    const float* Wv    = (const float*)d_in[5];
    const float* bv    = (const float*)d_in[6];
    const float* gamma = (const float*)d_in[7];
    float* out = (float*)d_out;

    char* ws = (char*)d_ws;
    const size_t MB = 1024 * 1024;
    __bf16* xt = (__bf16*)ws;                      // 16 MiB
    __bf16* Qt = (__bf16*)(ws + 16 * MB);          //  2 MiB (tiled)
    __bf16* Kt = (__bf16*)(ws + 18 * MB);          //  2 MiB (tiled)
    __bf16* Vb = (__bf16*)(ws + 20 * MB);          // 16 MiB (tiled)

    k_transpose<<<2048, 256, 0, stream>>>(x, xt);
    k_qkv<<<2560, 256, 0, stream>>>(Wq, bq, Wk, bk, Wv, bv, xt, Qt, Kt, Vb);
    k_attn<<<512, 256, 0, stream>>>(Qt, Kt, Vb, x, gamma, out);
}

// Round 14
// 137.901 us; speedup vs baseline: 1.3345x; 1.2126x over previous
//
#include <hip/hip_runtime.h>
#include <hip/hip_bf16.h>

#define C_DIM 256
#define C8 32
#define N_DIM 4096
#define B_DIM 8
#define KSTEPS 64    // 64 steps x 32 keys = 2048 keys per wave (key half)

using bf16x8 = __attribute__((ext_vector_type(8))) __bf16;
using f32x4  = __attribute__((ext_vector_type(4))) float;
using f32x16 = __attribute__((ext_vector_type(16))) float;
using uint2v = __attribute__((ext_vector_type(2))) unsigned;

#define LOG2E 1.44269504088896f

// Tiled layouts (fragment-major, per batch):
//   Q/K: idx(n,d) = (n>>5)*1024 + (d>>3)*256 + (n&31)*8 + (d&7)    [N*32 elems]
//   V  : idx(c,n) = (n>>4)*4096 + ((n>>3)&1)*2048 + c*8 + (n&7)    [N*C elems]

// ---------------------------------------------------------------------------
// Kernel 1 (fused): x transpose (LDS) + QKV projection -> TILED outputs.
// One block per (b, 64-wide n-tile). Phase A: stage x[b,:,n0:n0+64] into a
// bf16 [64][264] LDS tile via the conflict-free 64x65 f32 staging transpose.
// Phase B: 5 d-tiles x MFMA against the LDS tile. Q pre-scaled by log2(e).
// ---------------------------------------------------------------------------
__global__ __launch_bounds__(256) void k_qkv(
    const float* __restrict__ x,
    const float* __restrict__ Wq, const float* __restrict__ bq,
    const float* __restrict__ Wk, const float* __restrict__ bk,
    const float* __restrict__ Wv, const float* __restrict__ bv,
    __bf16* __restrict__ Qt, __bf16* __restrict__ Kt, __bf16* __restrict__ Vb)
{
    __shared__ __align__(16) float  tile[64][65];   // 16.6 KB
    __shared__ __align__(16) __bf16 xs[64][264];    // 33.8 KB, [n][c], pad 8

    int bid = blockIdx.x;       // 512 = 8 b x 64 nt
    int b   = bid & 7;
    int nt  = bid >> 3;
    int n0  = nt * 64;
    int t   = threadIdx.x;

    const float* xb = x + (size_t)b * C_DIM * N_DIM;
#pragma unroll
    for (int ct = 0; ct < 4; ct++) {
        int c0 = ct * 64;
#pragma unroll
        for (int k = 0; k < 16; k++) {
            int idx = k * 256 + t;
            int i = idx >> 6, j = idx & 63;
            tile[i][j] = xb[(size_t)(c0 + i) * N_DIM + n0 + j];
        }
        __syncthreads();
#pragma unroll
        for (int k = 0; k < 16; k++) {
            int idx = k * 256 + t;
            int nl = idx >> 6, cl = idx & 63;
            xs[nl][c0 + cl] = (__bf16)tile[cl][nl];
        }
        __syncthreads();
    }

    int wid = t >> 6, lane = t & 63;
    int lg = lane >> 4, li = lane & 15;

    __bf16* Qtb = Qt + (size_t)b * (N_DIM * 32);
    __bf16* Ktb = Kt + (size_t)b * (N_DIM * 32);
    __bf16* Vtb = Vb + (size_t)b * (N_DIM * C_DIM);

#pragma unroll
    for (int dt = 0; dt < 5; dt++) {
        int d0w = dt * 64 + wid * 16;
        int drow = d0w + li;
        const float* wrow;
        if (drow < 32)        wrow = Wq + drow * C_DIM;
        else if (drow < 64)   wrow = Wk + (drow - 32) * C_DIM;
        else                  wrow = Wv + (drow - 64) * C_DIM;

        f32x4 acc[4] = {};
#pragma unroll
        for (int ksx = 0; ksx < 8; ksx++) {
            int c0 = ksx * 32 + lg * 8;
            float4 w0 = *(const float4*)(wrow + c0);
            float4 w1 = *(const float4*)(wrow + c0 + 4);
            bf16x8 af;
            af[0] = (__bf16)w0.x; af[1] = (__bf16)w0.y;
            af[2] = (__bf16)w0.z; af[3] = (__bf16)w0.w;
            af[4] = (__bf16)w1.x; af[5] = (__bf16)w1.y;
            af[6] = (__bf16)w1.z; af[7] = (__bf16)w1.w;
#pragma unroll
            for (int ns = 0; ns < 4; ns++) {
                bf16x8 bfr = *(const bf16x8*)(&xs[ns * 16 + li][ksx * 32 + lg * 8]);
                acc[ns] = __builtin_amdgcn_mfma_f32_16x16x32_bf16(af, bfr, acc[ns], 0, 0, 0);
            }
        }
#pragma unroll
        for (int r = 0; r < 4; r++) {
            int d = d0w + lg * 4 + r;
            float bias = (d < 32) ? bq[d] : (d < 64) ? bk[d - 32] : bv[d - 64];
#pragma unroll
            for (int ns = 0; ns < 4; ns++) {
                int n = n0 + ns * 16 + li;
                float v = acc[ns][r] + bias;
                if (d < 32) {
                    int dd = d;
                    Qtb[((n >> 5) << 10) + ((dd >> 3) << 8) + ((n & 31) << 3) + (dd & 7)]
                        = (__bf16)(v * LOG2E);
                } else if (d < 64) {
                    int dd = d - 32;
                    Ktb[((n >> 5) << 10) + ((dd >> 3) << 8) + ((n & 31) << 3) + (dd & 7)]
                        = (__bf16)v;
                } else {
                    int c = d - 64;
                    Vtb[((n >> 4) << 12) + (((n >> 3) & 1) << 11) + (c << 3) + (n & 7)]
                        = (__bf16)v;
                }
            }
        }
    }
}

// ---------------------------------------------------------------------------
// helpers (numerics verified R7-R13: absmax matched)
// ---------------------------------------------------------------------------
static __device__ __forceinline__ unsigned pack2(float a, float b) {
    union { __bf16 h[2]; unsigned u; } c;
    c.h[0] = (__bf16)a; c.h[1] = (__bf16)b; return c.u;
}
static __device__ __forceinline__ bf16x8 mkfrag(unsigned d0, unsigned d1, unsigned d2, unsigned d3) {
    union { unsigned u[4]; bf16x8 v; } r;
    r.u[0] = d0; r.u[1] = d1; r.u[2] = d2; r.u[3] = d3; return r.v;
}
static __device__ __forceinline__ uint2v plswap(unsigned a, unsigned b) {
#if __has_builtin(__builtin_amdgcn_permlane32_swap)
    return __builtin_amdgcn_permlane32_swap(a, b, false, false);
#else
    unsigned ax = (unsigned)__shfl_xor((int)a, 32);
    unsigned bx = (unsigned)__shfl_xor((int)b, 32);
    int hi = (threadIdx.x >> 5) & 1;
    uint2v r;
    r.x = hi ? bx : a;
    r.y = hi ? b  : ax;
    return r;
#endif
}
// S~ (K·Q^T) 32x32 C/D block -> exp2 (no shift: cancels in O/l)
// -> two PV B-fragments (16-key slices) + l partials.
static __device__ __forceinline__ void soft_pack(
    const f32x16& s, float& l, bf16x8& f0, bf16x8& f1)
{
    float p[16];
#pragma unroll
    for (int r = 0; r < 16; r++) p[r] = __builtin_amdgcn_exp2f(s[r]);
    float lp = 0.f;
#pragma unroll
    for (int r = 0; r < 16; r++) lp += p[r];
    l += lp;
    unsigned a0 = pack2(p[0],  p[1]),  b0 = pack2(p[2],  p[3]);
    unsigned a1 = pack2(p[4],  p[5]),  b1 = pack2(p[6],  p[7]);
    unsigned a2 = pack2(p[8],  p[9]),  b2 = pack2(p[10], p[11]);
    unsigned a3 = pack2(p[12], p[13]), b3 = pack2(p[14], p[15]);
    uint2v rA0 = plswap(a0, a1), rB0 = plswap(b0, b1);
    uint2v rA1 = plswap(a2, a3), rB1 = plswap(b2, b3);
    f0 = mkfrag(rA0.x, rB0.x, rA0.y, rB0.y);   // keys 0..15
    f1 = mkfrag(rA1.x, rB1.x, rA1.y, rB1.y);   // keys 16..31
}

// ---------------------------------------------------------------------------
// Kernel 2: key-split flash attention with ROTATING V prefetch.
// Wave = 32q x 256ch x 2048 keys (key half). Zero softmax redundancy,
// 2 waves/SIMD. Each V fragment is reloaded with its step-I+1 value right
// after its last use in PV(I) -> ~full-step load-to-use distance with zero
// extra registers. QK(I+1) sits mid-PV so its latency is covered; softpack
// consumes s across the step boundary. Merge via bf16 LDS + ONE barrier.
// ---------------------------------------------------------------------------
__global__ __launch_bounds__(256, 2) void k_attn(
    const __bf16* __restrict__ Qt, const __bf16* __restrict__ Kt,
    const __bf16* __restrict__ Vb, const float* __restrict__ x,
    const float* __restrict__ gamma, float* __restrict__ out)
{
    __shared__ __bf16 accs[2][C_DIM][32];   // 32 KiB: ks=1 partial O
    __shared__ float  lbuf[2][32];

    int bid = blockIdx.x;            // 512 blocks, 2 per CU
    int b   = bid & 7;               // batch -> XCD affinity (K/V in 4MB L2)
    int qp  = bid >> 3;              // 0..63 : query-tile pair
    int wid  = threadIdx.x >> 6;
    int qsel = wid >> 1;             // which of the 2 query-tiles
    int ks   = wid & 1;              // key half
    int li  = threadIdx.x & 31;
    int hi  = (threadIdx.x >> 5) & 1;
    int n0q = (qp * 2 + qsel) * 32;

    const __bf16* Qtb = Qt + (size_t)b * (N_DIM * 32);
    const __bf16* Ktb = Kt + (size_t)b * (N_DIM * 32);
    const __bf16* Vtb = Vb + (size_t)b * (N_DIM * C_DIM);

    const __bf16* Qlp = Qtb + ((n0q >> 5) << 10) + (hi << 8) + (li << 3);
    bf16x8 qf0 = *(const bf16x8*)(Qlp);        // d 0-15
    bf16x8 qf1 = *(const bf16x8*)(Qlp + 512);  // d 16-31

    const __bf16* Klp = Ktb + ((size_t)(ks * KSTEPS) << 10) + (hi << 8) + (li << 3);
    const __bf16* Vlp = Vtb + ((size_t)(ks * KSTEPS) << 13) + (hi << 11) + (li << 3);

    f32x16 acc0 = {}, acc1 = {}, acc2 = {}, acc3 = {};
    f32x16 acc4 = {}, acc5 = {}, acc6 = {}, acc7 = {};
    float l0 = 0.f;

    bf16x8 kA0, kA1, kB0, kB1;
    bf16x8 v0a, v0b, v1a, v1b, v2a, v2b, v3a, v3b;
    bf16x8 v4a, v4b, v5a, v5b, v6a, v6b, v7a, v7b;
    f32x16 s;

#define KLOAD(D0, D1, S)                                                       \
    { const __bf16* Kn = Klp + ((size_t)(S) << 10);                            \
      D0 = *(const bf16x8*)(Kn); D1 = *(const bf16x8*)(Kn + 512); }

    // PV group g: consume v_g for step I, then rotate-load step I+1's frags.
#define PVG(G, VA, VB, P0, P1, VN)                                             \
    acc##G = __builtin_amdgcn_mfma_f32_32x32x16_bf16(VA, P0, acc##G, 0, 0, 0); \
    acc##G = __builtin_amdgcn_mfma_f32_32x32x16_bf16(VB, P1, acc##G, 0, 0, 0); \
    VA = *(const bf16x8*)((VN) + (G) * 256);                                   \
    VB = *(const bf16x8*)((VN) + 4096 + (G) * 256);

    // STEP(I): softpack(s(I)) -> PV groups 0-3 -> QK(I+1) -> KLOAD(I+2)
    //          -> PV groups 4-7.  V rotation targets step I+1 (clamped).
#define STEP(KU0, KU1, KL0, KL1, I)                                            \
    {                                                                          \
        bf16x8 p0, p1;                                                         \
        soft_pack(s, l0, p0, p1);                                              \
        int ni = ((I) + 1 < KSTEPS) ? (I) + 1 : KSTEPS - 1;                    \
        const __bf16* Vn = Vlp + ((size_t)ni << 13);                           \
        PVG(0, v0a, v0b, p0, p1, Vn)                                           \
        PVG(1, v1a, v1b, p0, p1, Vn)                                           \
        PVG(2, v2a, v2b, p0, p1, Vn)                                           \
        PVG(3, v3a, v3b, p0, p1, Vn)                                           \
        f32x16 z = {};                                                         \
        s = __builtin_amdgcn_mfma_f32_32x32x16_bf16(KU0, qf0, z, 0, 0, 0);     \
        s = __builtin_amdgcn_mfma_f32_32x32x16_bf16(KU1, qf1, s, 0, 0, 0);     \
        int ni2 = ((I) + 2 < KSTEPS) ? (I) + 2 : KSTEPS - 1;                   \
        KLOAD(KL0, KL1, ni2)                                                   \
        PVG(4, v4a, v4b, p0, p1, Vn)                                           \
        PVG(5, v5a, v5b, p0, p1, Vn)                                           \
        PVG(6, v6a, v6b, p0, p1, Vn)                                           \
        PVG(7, v7a, v7b, p0, p1, Vn)                                           \
    }

    // prologue: K(0),K(1); V(0); s = QK(0)
    KLOAD(kA0, kA1, 0)
    KLOAD(kB0, kB1, 1)
    v0a = *(const bf16x8*)(Vlp);          v0b = *(const bf16x8*)(Vlp + 4096);
    v1a = *(const bf16x8*)(Vlp + 256);    v1b = *(const bf16x8*)(Vlp + 4096 + 256);
    v2a = *(const bf16x8*)(Vlp + 512);    v2b = *(const bf16x8*)(Vlp + 4096 + 512);
    v3a = *(const bf16x8*)(Vlp + 768);    v3b = *(const bf16x8*)(Vlp + 4096 + 768);
    v4a = *(const bf16x8*)(Vlp + 1024);   v4b = *(const bf16x8*)(Vlp + 4096 + 1024);
    v5a = *(const bf16x8*)(Vlp + 1280);   v5b = *(const bf16x8*)(Vlp + 4096 + 1280);
    v6a = *(const bf16x8*)(Vlp + 1536);   v6b = *(const bf16x8*)(Vlp + 4096 + 1536);
    v7a = *(const bf16x8*)(Vlp + 1792);   v7b = *(const bf16x8*)(Vlp + 4096 + 1792);
    {
        f32x16 z = {};
        s = __builtin_amdgcn_mfma_f32_32x32x16_bf16(kA0, qf0, z, 0, 0, 0);
        s = __builtin_amdgcn_mfma_f32_32x32x16_bf16(kA1, qf1, s, 0, 0, 0);
    }

    for (int i = 0; i < KSTEPS; i += 2) {
        STEP(kB0, kB1, kA0, kA1, i)        // QK(I+1) uses kB=K(I+1)
        STEP(kA0, kA1, kB0, kB1, i + 1)    // QK(I+2) uses kA=K(I+2)
    }

#undef STEP
#undef PVG
#undef KLOAD

    // ---- merge the two key halves: ks=1 -> LDS (bf16 partials + l), barrier,
    //      ks=0 adds and runs the fused epilogue.
    float lv = l0 + __shfl_xor(l0, 32);   // per-lane query li's partial sum

    if (ks == 1) {
        if (hi == 0) lbuf[qsel][li] = lv;
#define SPILL_ACC(A, G)                                                        \
        _Pragma("unroll")                                                      \
        for (int rg = 0; rg < 16; rg++) {                                      \
            int row = (rg & 3) + 8 * (rg >> 2) + 4 * hi;                       \
            accs[qsel][(G) * 32 + row][li] = (__bf16)A[rg];                    \
        }
        SPILL_ACC(acc0, 0) SPILL_ACC(acc1, 1) SPILL_ACC(acc2, 2) SPILL_ACC(acc3, 3)
        SPILL_ACC(acc4, 4) SPILL_ACC(acc5, 5) SPILL_ACC(acc6, 6) SPILL_ACC(acc7, 7)
#undef SPILL_ACC
    }
    __syncthreads();
    if (ks == 0) {
        float lt = lv + lbuf[qsel][li];
        float linv = gamma[0] / lt;
#define STORE_ACC(A, G)                                                        \
        _Pragma("unroll")                                                      \
        for (int rg = 0; rg < 16; rg++) {                                      \
            int row = (rg & 3) + 8 * (rg >> 2) + 4 * hi;                       \
            int c = (G) * 32 + row;                                            \
            size_t idx = ((size_t)b * C_DIM + c) * N_DIM + (n0q + li);         \
            float o = A[rg] + (float)accs[qsel][c][li];                        \
            out[idx] = o * linv + x[idx];                                      \
        }
        STORE_ACC(acc0, 0) STORE_ACC(acc1, 1) STORE_ACC(acc2, 2) STORE_ACC(acc3, 3)
        STORE_ACC(acc4, 4) STORE_ACC(acc5, 5) STORE_ACC(acc6, 6) STORE_ACC(acc7, 7)
#undef STORE_ACC
    }
}

// ---------------------------------------------------------------------------
extern "C" void kernel_launch(void* const* d_in, const int* in_sizes, int n_in,
                              void* d_out, int out_size, void* d_ws, size_t ws_size,
                              hipStream_t stream)
{
    const float* x     = (const float*)d_in[0];
    const float* Wq    = (const float*)d_in[1];
    const float* bq    = (const float*)d_in[2];
    const float* Wk    = (const float*)d_in[3];
    const float* bk    = (const float*)d_in[4];
    const float* Wv    = (const float*)d_in[5];
    const float* bv    = (const float*)d_in[6];
    const float* gamma = (const float*)d_in[7];
    float* out = (float*)d_out;

    char* ws = (char*)d_ws;
    const size_t MB = 1024 * 1024;
    __bf16* Qt = (__bf16*)ws;                      //  2 MiB (tiled)
    __bf16* Kt = (__bf16*)(ws + 2 * MB);           //  2 MiB (tiled)
    __bf16* Vb = (__bf16*)(ws + 4 * MB);           // 16 MiB (tiled)

    k_qkv<<<512, 256, 0, stream>>>(x, Wq, bq, Wk, bk, Wv, bv, Qt, Kt, Vb);
    k_attn<<<512, 256, 0, stream>>>(Qt, Kt, Vb, x, gamma, out);
}

// Round 15
// 136.761 us; speedup vs baseline: 1.3456x; 1.0083x over previous
//
#include <hip/hip_runtime.h>
#include <hip/hip_bf16.h>

#define C_DIM 256
#define C8 32
#define N_DIM 4096
#define B_DIM 8
#define KSTEPS 64    // 64 steps x 32 keys = 2048 keys per wave (key half)

using bf16x8 = __attribute__((ext_vector_type(8))) __bf16;
using f32x4  = __attribute__((ext_vector_type(4))) float;
using f32x16 = __attribute__((ext_vector_type(16))) float;
using uint2v = __attribute__((ext_vector_type(2))) unsigned;

#define LOG2E 1.44269504088896f

// Tiled layouts (fragment-major, per batch):
//   Q/K: idx(n,d) = (n>>5)*1024 + (d>>3)*256 + (n&31)*8 + (d&7)    [N*32 elems]
//   V  : idx(c,n) = (n>>4)*4096 + ((n>>3)&1)*2048 + c*8 + (n&7)    [N*C elems]

// ---------------------------------------------------------------------------
// Kernel 1 (fused): x transpose (LDS) + QKV projection -> TILED outputs.
// ---------------------------------------------------------------------------
__global__ __launch_bounds__(256) void k_qkv(
    const float* __restrict__ x,
    const float* __restrict__ Wq, const float* __restrict__ bq,
    const float* __restrict__ Wk, const float* __restrict__ bk,
    const float* __restrict__ Wv, const float* __restrict__ bv,
    __bf16* __restrict__ Qt, __bf16* __restrict__ Kt, __bf16* __restrict__ Vb)
{
    __shared__ __align__(16) float  tile[64][65];   // 16.6 KB
    __shared__ __align__(16) __bf16 xs[64][264];    // 33.8 KB, [n][c], pad 8

    int bid = blockIdx.x;       // 512 = 8 b x 64 nt
    int b   = bid & 7;
    int nt  = bid >> 3;
    int n0  = nt * 64;
    int t   = threadIdx.x;

    const float* xb = x + (size_t)b * C_DIM * N_DIM;
#pragma unroll
    for (int ct = 0; ct < 4; ct++) {
        int c0 = ct * 64;
#pragma unroll
        for (int k = 0; k < 16; k++) {
            int idx = k * 256 + t;
            int i = idx >> 6, j = idx & 63;
            tile[i][j] = xb[(size_t)(c0 + i) * N_DIM + n0 + j];
        }
        __syncthreads();
#pragma unroll
        for (int k = 0; k < 16; k++) {
            int idx = k * 256 + t;
            int nl = idx >> 6, cl = idx & 63;
            xs[nl][c0 + cl] = (__bf16)tile[cl][nl];
        }
        __syncthreads();
    }

    int wid = t >> 6, lane = t & 63;
    int lg = lane >> 4, li = lane & 15;

    __bf16* Qtb = Qt + (size_t)b * (N_DIM * 32);
    __bf16* Ktb = Kt + (size_t)b * (N_DIM * 32);
    __bf16* Vtb = Vb + (size_t)b * (N_DIM * C_DIM);

#pragma unroll
    for (int dt = 0; dt < 5; dt++) {
        int d0w = dt * 64 + wid * 16;
        int drow = d0w + li;
        const float* wrow;
        if (drow < 32)        wrow = Wq + drow * C_DIM;
        else if (drow < 64)   wrow = Wk + (drow - 32) * C_DIM;
        else                  wrow = Wv + (drow - 64) * C_DIM;

        f32x4 acc[4] = {};
#pragma unroll
        for (int ksx = 0; ksx < 8; ksx++) {
            int c0 = ksx * 32 + lg * 8;
            float4 w0 = *(const float4*)(wrow + c0);
            float4 w1 = *(const float4*)(wrow + c0 + 4);
            bf16x8 af;
            af[0] = (__bf16)w0.x; af[1] = (__bf16)w0.y;
            af[2] = (__bf16)w0.z; af[3] = (__bf16)w0.w;
            af[4] = (__bf16)w1.x; af[5] = (__bf16)w1.y;
            af[6] = (__bf16)w1.z; af[7] = (__bf16)w1.w;
#pragma unroll
            for (int ns = 0; ns < 4; ns++) {
                bf16x8 bfr = *(const bf16x8*)(&xs[ns * 16 + li][ksx * 32 + lg * 8]);
                acc[ns] = __builtin_amdgcn_mfma_f32_16x16x32_bf16(af, bfr, acc[ns], 0, 0, 0);
            }
        }
#pragma unroll
        for (int r = 0; r < 4; r++) {
            int d = d0w + lg * 4 + r;
            float bias = (d < 32) ? bq[d] : (d < 64) ? bk[d - 32] : bv[d - 64];
#pragma unroll
            for (int ns = 0; ns < 4; ns++) {
                int n = n0 + ns * 16 + li;
                float v = acc[ns][r] + bias;
                if (d < 32) {
                    int dd = d;
                    Qtb[((n >> 5) << 10) + ((dd >> 3) << 8) + ((n & 31) << 3) + (dd & 7)]
                        = (__bf16)(v * LOG2E);
                } else if (d < 64) {
                    int dd = d - 32;
                    Ktb[((n >> 5) << 10) + ((dd >> 3) << 8) + ((n & 31) << 3) + (dd & 7)]
                        = (__bf16)v;
                } else {
                    int c = d - 64;
                    Vtb[((n >> 4) << 12) + (((n >> 3) & 1) << 11) + (c << 3) + (n & 7)]
                        = (__bf16)v;
                }
            }
        }
    }
}

// ---------------------------------------------------------------------------
// helpers (numerics verified R7-R14: absmax matched)
// ---------------------------------------------------------------------------
static __device__ __forceinline__ unsigned pack2(float a, float b) {
    union { __bf16 h[2]; unsigned u; } c;
    c.h[0] = (__bf16)a; c.h[1] = (__bf16)b; return c.u;
}
static __device__ __forceinline__ bf16x8 mkfrag(unsigned d0, unsigned d1, unsigned d2, unsigned d3) {
    union { unsigned u[4]; bf16x8 v; } r;
    r.u[0] = d0; r.u[1] = d1; r.u[2] = d2; r.u[3] = d3; return r.v;
}
static __device__ __forceinline__ uint2v plswap(unsigned a, unsigned b) {
#if __has_builtin(__builtin_amdgcn_permlane32_swap)
    return __builtin_amdgcn_permlane32_swap(a, b, false, false);
#else
    unsigned ax = (unsigned)__shfl_xor((int)a, 32);
    unsigned bx = (unsigned)__shfl_xor((int)b, 32);
    int hi = (threadIdx.x >> 5) & 1;
    uint2v r;
    r.x = hi ? bx : a;
    r.y = hi ? b  : ax;
    return r;
#endif
}
// S~ (K·Q^T) 32x32 C/D block -> exp2 (no shift: cancels in O/l)
// -> two PV B-fragments (16-key slices) + l partials.
static __device__ __forceinline__ void soft_pack(
    const f32x16& s, float& l, bf16x8& f0, bf16x8& f1)
{
    float p[16];
#pragma unroll
    for (int r = 0; r < 16; r++) p[r] = __builtin_amdgcn_exp2f(s[r]);
    float lp = 0.f;
#pragma unroll
    for (int r = 0; r < 16; r++) lp += p[r];
    l += lp;
    unsigned a0 = pack2(p[0],  p[1]),  b0 = pack2(p[2],  p[3]);
    unsigned a1 = pack2(p[4],  p[5]),  b1 = pack2(p[6],  p[7]);
    unsigned a2 = pack2(p[8],  p[9]),  b2 = pack2(p[10], p[11]);
    unsigned a3 = pack2(p[12], p[13]), b3 = pack2(p[14], p[15]);
    uint2v rA0 = plswap(a0, a1), rB0 = plswap(b0, b1);
    uint2v rA1 = plswap(a2, a3), rB1 = plswap(b2, b3);
    f0 = mkfrag(rA0.x, rB0.x, rA0.y, rB0.y);   // keys 0..15
    f1 = mkfrag(rA1.x, rB1.x, rA1.y, rB1.y);   // keys 16..31
}

// ---------------------------------------------------------------------------
// Kernel 2: key-split flash attention (R13 step structure: BATCHED V load
// clauses) + s_setprio around the PV MFMA cluster (T5) to desynchronize the
// two co-resident waves. Wave = 32q x 256ch x 2048 keys; zero softmax
// redundancy; merge via bf16 LDS + ONE barrier.
// ---------------------------------------------------------------------------
__global__ __launch_bounds__(256, 2) void k_attn(
    const __bf16* __restrict__ Qt, const __bf16* __restrict__ Kt,
    const __bf16* __restrict__ Vb, const float* __restrict__ x,
    const float* __restrict__ gamma, float* __restrict__ out)
{
    __shared__ __bf16 accs[2][C_DIM][32];   // 32 KiB: ks=1 partial O
    __shared__ float  lbuf[2][32];

    int bid = blockIdx.x;            // 512 blocks, 2 per CU
    int b   = bid & 7;               // batch -> XCD affinity (K/V in 4MB L2)
    int qp  = bid >> 3;              // 0..63 : query-tile pair
    int wid  = threadIdx.x >> 6;
    int qsel = wid >> 1;             // which of the 2 query-tiles
    int ks   = wid & 1;              // key half
    int li  = threadIdx.x & 31;
    int hi  = (threadIdx.x >> 5) & 1;
    int n0q = (qp * 2 + qsel) * 32;

    const __bf16* Qtb = Qt + (size_t)b * (N_DIM * 32);
    const __bf16* Ktb = Kt + (size_t)b * (N_DIM * 32);
    const __bf16* Vtb = Vb + (size_t)b * (N_DIM * C_DIM);

    const __bf16* Qlp = Qtb + ((n0q >> 5) << 10) + (hi << 8) + (li << 3);
    bf16x8 qf0 = *(const bf16x8*)(Qlp);        // d 0-15
    bf16x8 qf1 = *(const bf16x8*)(Qlp + 512);  // d 16-31

    const __bf16* Klp = Ktb + ((size_t)(ks * KSTEPS) << 10) + (hi << 8) + (li << 3);
    const __bf16* Vlp = Vtb + ((size_t)(ks * KSTEPS) << 13) + (hi << 11) + (li << 3);

    f32x16 acc0 = {}, acc1 = {}, acc2 = {}, acc3 = {};
    f32x16 acc4 = {}, acc5 = {}, acc6 = {}, acc7 = {};
    float l0 = 0.f;

    bf16x8 kA0, kA1, kB0, kB1;

#define KLOAD(D0, D1, S)                                                       \
    { const __bf16* Kn = Klp + ((size_t)(S) << 10);                            \
      D0 = *(const bf16x8*)(Kn); D1 = *(const bf16x8*)(Kn + 512); }

    // STEP(I): s = QK(I) from KU; prefetch K(KS2)->KL; V in 2 batched chunks
    // of 8 loads (clause-friendly); PV under setprio(1).
#define STEP(KU0, KU1, KL0, KL1, KS2, I)                                       \
    {                                                                          \
        f32x16 z = {};                                                         \
        f32x16 s = __builtin_amdgcn_mfma_f32_32x32x16_bf16(KU0, qf0, z, 0, 0, 0); \
        s = __builtin_amdgcn_mfma_f32_32x32x16_bf16(KU1, qf1, s, 0, 0, 0);     \
        KLOAD(KL0, KL1, KS2)                                                   \
        const __bf16* Vn = Vlp + ((size_t)(I) << 13);                          \
        bf16x8 v0 = *(const bf16x8*)(Vn);                                      \
        bf16x8 v1 = *(const bf16x8*)(Vn + 4096);                               \
        bf16x8 v2 = *(const bf16x8*)(Vn + 256);                                \
        bf16x8 v3 = *(const bf16x8*)(Vn + 4096 + 256);                         \
        bf16x8 v4 = *(const bf16x8*)(Vn + 512);                                \
        bf16x8 v5 = *(const bf16x8*)(Vn + 4096 + 512);                         \
        bf16x8 v6 = *(const bf16x8*)(Vn + 768);                                \
        bf16x8 v7 = *(const bf16x8*)(Vn + 4096 + 768);                         \
        bf16x8 p0, p1;                                                         \
        soft_pack(s, l0, p0, p1);                                              \
        __builtin_amdgcn_s_setprio(1);                                         \
        acc0 = __builtin_amdgcn_mfma_f32_32x32x16_bf16(v0, p0, acc0, 0, 0, 0); \
        acc0 = __builtin_amdgcn_mfma_f32_32x32x16_bf16(v1, p1, acc0, 0, 0, 0); \
        bf16x8 w0 = *(const bf16x8*)(Vn + 1024);                               \
        bf16x8 w1 = *(const bf16x8*)(Vn + 4096 + 1024);                        \
        acc1 = __builtin_amdgcn_mfma_f32_32x32x16_bf16(v2, p0, acc1, 0, 0, 0); \
        acc1 = __builtin_amdgcn_mfma_f32_32x32x16_bf16(v3, p1, acc1, 0, 0, 0); \
        bf16x8 w2 = *(const bf16x8*)(Vn + 1280);                               \
        bf16x8 w3 = *(const bf16x8*)(Vn + 4096 + 1280);                        \
        acc2 = __builtin_amdgcn_mfma_f32_32x32x16_bf16(v4, p0, acc2, 0, 0, 0); \
        acc2 = __builtin_amdgcn_mfma_f32_32x32x16_bf16(v5, p1, acc2, 0, 0, 0); \
        bf16x8 w4 = *(const bf16x8*)(Vn + 1536);                               \
        bf16x8 w5 = *(const bf16x8*)(Vn + 4096 + 1536);                        \
        acc3 = __builtin_amdgcn_mfma_f32_32x32x16_bf16(v6, p0, acc3, 0, 0, 0); \
        acc3 = __builtin_amdgcn_mfma_f32_32x32x16_bf16(v7, p1, acc3, 0, 0, 0); \
        bf16x8 w6 = *(const bf16x8*)(Vn + 1792);                               \
        bf16x8 w7 = *(const bf16x8*)(Vn + 4096 + 1792);                        \
        acc4 = __builtin_amdgcn_mfma_f32_32x32x16_bf16(w0, p0, acc4, 0, 0, 0); \
        acc4 = __builtin_amdgcn_mfma_f32_32x32x16_bf16(w1, p1, acc4, 0, 0, 0); \
        acc5 = __builtin_amdgcn_mfma_f32_32x32x16_bf16(w2, p0, acc5, 0, 0, 0); \
        acc5 = __builtin_amdgcn_mfma_f32_32x32x16_bf16(w3, p1, acc5, 0, 0, 0); \
        acc6 = __builtin_amdgcn_mfma_f32_32x32x16_bf16(w4, p0, acc6, 0, 0, 0); \
        acc6 = __builtin_amdgcn_mfma_f32_32x32x16_bf16(w5, p1, acc6, 0, 0, 0); \
        acc7 = __builtin_amdgcn_mfma_f32_32x32x16_bf16(w6, p0, acc7, 0, 0, 0); \
        acc7 = __builtin_amdgcn_mfma_f32_32x32x16_bf16(w7, p1, acc7, 0, 0, 0); \
        __builtin_amdgcn_s_setprio(0);                                         \
    }

    // prologue: K(0), K(1)
    KLOAD(kA0, kA1, 0)
    KLOAD(kB0, kB1, 1)

    for (int i = 0; i < KSTEPS - 2; i += 2) {
        STEP(kA0, kA1, kA0, kA1, i + 2, i)
        STEP(kB0, kB1, kB0, kB1, i + 3, i + 1)
    }
    STEP(kA0, kA1, kA0, kA1, KSTEPS - 1, KSTEPS - 2)   // K reload: harmless
    STEP(kB0, kB1, kB0, kB1, KSTEPS - 1, KSTEPS - 1)

#undef STEP
#undef KLOAD

    // ---- merge the two key halves: ks=1 -> LDS (bf16 partials + l), barrier,
    //      ks=0 adds and runs the fused epilogue.
    float lv = l0 + __shfl_xor(l0, 32);   // per-lane query li's partial sum

    if (ks == 1) {
        if (hi == 0) lbuf[qsel][li] = lv;
#define SPILL_ACC(A, G)                                                        \
        _Pragma("unroll")                                                      \
        for (int rg = 0; rg < 16; rg++) {                                      \
            int row = (rg & 3) + 8 * (rg >> 2) + 4 * hi;                       \
            accs[qsel][(G) * 32 + row][li] = (__bf16)A[rg];                    \
        }
        SPILL_ACC(acc0, 0) SPILL_ACC(acc1, 1) SPILL_ACC(acc2, 2) SPILL_ACC(acc3, 3)
        SPILL_ACC(acc4, 4) SPILL_ACC(acc5, 5) SPILL_ACC(acc6, 6) SPILL_ACC(acc7, 7)
#undef SPILL_ACC
    }
    __syncthreads();
    if (ks == 0) {
        float lt = lv + lbuf[qsel][li];
        float linv = gamma[0] / lt;
#define STORE_ACC(A, G)                                                        \
        _Pragma("unroll")                                                      \
        for (int rg = 0; rg < 16; rg++) {                                      \
            int row = (rg & 3) + 8 * (rg >> 2) + 4 * hi;                       \
            int c = (G) * 32 + row;                                            \
            size_t idx = ((size_t)b * C_DIM + c) * N_DIM + (n0q + li);         \
            float o = A[rg] + (float)accs[qsel][c][li];                        \
            out[idx] = o * linv + x[idx];                                      \
        }
        STORE_ACC(acc0, 0) STORE_ACC(acc1, 1) STORE_ACC(acc2, 2) STORE_ACC(acc3, 3)
        STORE_ACC(acc4, 4) STORE_ACC(acc5, 5) STORE_ACC(acc6, 6) STORE_ACC(acc7, 7)
#undef STORE_ACC
    }
}

// ---------------------------------------------------------------------------
extern "C" void kernel_launch(void* const* d_in, const int* in_sizes, int n_in,
                              void* d_out, int out_size, void* d_ws, size_t ws_size,
                              hipStream_t stream)
{
    const float* x     = (const float*)d_in[0];
    const float* Wq    = (const float*)d_in[1];
    const float* bq    = (const float*)d_in[2];
    const float* Wk    = (const float*)d_in[3];
    const float* bk    = (const float*)d_in[4];
    const float* Wv    = (const float*)d_in[5];
    const float* bv    = (const float*)d_in[6];
    const float* gamma = (const float*)d_in[7];
    float* out = (float*)d_out;

    char* ws = (char*)d_ws;
    const size_t MB = 1024 * 1024;
    __bf16* Qt = (__bf16*)ws;                      //  2 MiB (tiled)
    __bf16* Kt = (__bf16*)(ws + 2 * MB);           //  2 MiB (tiled)
    __bf16* Vb = (__bf16*)(ws + 4 * MB);           // 16 MiB (tiled)

    k_qkv<<<512, 256, 0, stream>>>(x, Wq, bq, Wk, bk, Wv, bv, Qt, Kt, Vb);
    k_attn<<<512, 256, 0, stream>>>(Qt, Kt, Vb, x, gamma, out);
}

// Round 16
// 131.724 us; speedup vs baseline: 1.3971x; 1.0382x over previous
//
#include <hip/hip_runtime.h>
#include <hip/hip_bf16.h>

#define C_DIM 256
#define C8 32
#define N_DIM 4096
#define B_DIM 8
#define KSTEPS 64    // 64 steps x 32 keys = 2048 keys per wave (key half)

using bf16x8 = __attribute__((ext_vector_type(8))) __bf16;
using f32x4  = __attribute__((ext_vector_type(4))) float;
using f32x16 = __attribute__((ext_vector_type(16))) float;
using uint2v = __attribute__((ext_vector_type(2))) unsigned;

#define LOG2E 1.44269504088896f

// Tiled layouts (fragment-major, per batch):
//   Q/K: idx(n,d) = (n>>5)*1024 + (d>>3)*256 + (n&31)*8 + (d&7)    [N*32 elems]
//   V  : idx(c,n) = (n>>4)*4096 + ((n>>3)&1)*2048 + c*8 + (n&7)    [N*C elems]

// ---------------------------------------------------------------------------
// Kernel 1 (fused): x transpose (LDS) + QKV projection -> TILED outputs.
// ---------------------------------------------------------------------------
__global__ __launch_bounds__(256) void k_qkv(
    const float* __restrict__ x,
    const float* __restrict__ Wq, const float* __restrict__ bq,
    const float* __restrict__ Wk, const float* __restrict__ bk,
    const float* __restrict__ Wv, const float* __restrict__ bv,
    __bf16* __restrict__ Qt, __bf16* __restrict__ Kt, __bf16* __restrict__ Vb)
{
    __shared__ __align__(16) float  tile[64][65];   // 16.6 KB
    __shared__ __align__(16) __bf16 xs[64][264];    // 33.8 KB, [n][c], pad 8

    int bid = blockIdx.x;       // 512 = 8 b x 64 nt
    int b   = bid & 7;
    int nt  = bid >> 3;
    int n0  = nt * 64;
    int t   = threadIdx.x;

    const float* xb = x + (size_t)b * C_DIM * N_DIM;
#pragma unroll
    for (int ct = 0; ct < 4; ct++) {
        int c0 = ct * 64;
#pragma unroll
        for (int k = 0; k < 16; k++) {
            int idx = k * 256 + t;
            int i = idx >> 6, j = idx & 63;
            tile[i][j] = xb[(size_t)(c0 + i) * N_DIM + n0 + j];
        }
        __syncthreads();
#pragma unroll
        for (int k = 0; k < 16; k++) {
            int idx = k * 256 + t;
            int nl = idx >> 6, cl = idx & 63;
            xs[nl][c0 + cl] = (__bf16)tile[cl][nl];
        }
        __syncthreads();
    }

    int wid = t >> 6, lane = t & 63;
    int lg = lane >> 4, li = lane & 15;

    __bf16* Qtb = Qt + (size_t)b * (N_DIM * 32);
    __bf16* Ktb = Kt + (size_t)b * (N_DIM * 32);
    __bf16* Vtb = Vb + (size_t)b * (N_DIM * C_DIM);

#pragma unroll
    for (int dt = 0; dt < 5; dt++) {
        int d0w = dt * 64 + wid * 16;
        int drow = d0w + li;
        const float* wrow;
        if (drow < 32)        wrow = Wq + drow * C_DIM;
        else if (drow < 64)   wrow = Wk + (drow - 32) * C_DIM;
        else                  wrow = Wv + (drow - 64) * C_DIM;

        f32x4 acc[4] = {};
#pragma unroll
        for (int ksx = 0; ksx < 8; ksx++) {
            int c0 = ksx * 32 + lg * 8;
            float4 w0 = *(const float4*)(wrow + c0);
            float4 w1 = *(const float4*)(wrow + c0 + 4);
            bf16x8 af;
            af[0] = (__bf16)w0.x; af[1] = (__bf16)w0.y;
            af[2] = (__bf16)w0.z; af[3] = (__bf16)w0.w;
            af[4] = (__bf16)w1.x; af[5] = (__bf16)w1.y;
            af[6] = (__bf16)w1.z; af[7] = (__bf16)w1.w;
#pragma unroll
            for (int ns = 0; ns < 4; ns++) {
                bf16x8 bfr = *(const bf16x8*)(&xs[ns * 16 + li][ksx * 32 + lg * 8]);
                acc[ns] = __builtin_amdgcn_mfma_f32_16x16x32_bf16(af, bfr, acc[ns], 0, 0, 0);
            }
        }
#pragma unroll
        for (int r = 0; r < 4; r++) {
            int d = d0w + lg * 4 + r;
            float bias = (d < 32) ? bq[d] : (d < 64) ? bk[d - 32] : bv[d - 64];
#pragma unroll
            for (int ns = 0; ns < 4; ns++) {
                int n = n0 + ns * 16 + li;
                float v = acc[ns][r] + bias;
                if (d < 32) {
                    int dd = d;
                    Qtb[((n >> 5) << 10) + ((dd >> 3) << 8) + ((n & 31) << 3) + (dd & 7)]
                        = (__bf16)(v * LOG2E);
                } else if (d < 64) {
                    int dd = d - 32;
                    Ktb[((n >> 5) << 10) + ((dd >> 3) << 8) + ((n & 31) << 3) + (dd & 7)]
                        = (__bf16)v;
                } else {
                    int c = d - 64;
                    Vtb[((n >> 4) << 12) + (((n >> 3) & 1) << 11) + (c << 3) + (n & 7)]
                        = (__bf16)v;
                }
            }
        }
    }
}

// ---------------------------------------------------------------------------
// helpers (numerics verified R7-R15: absmax matched)
// ---------------------------------------------------------------------------
static __device__ __forceinline__ unsigned pack2(float a, float b) {
    union { __bf16 h[2]; unsigned u; } c;
    c.h[0] = (__bf16)a; c.h[1] = (__bf16)b; return c.u;
}
static __device__ __forceinline__ bf16x8 mkfrag(unsigned d0, unsigned d1, unsigned d2, unsigned d3) {
    union { unsigned u[4]; bf16x8 v; } r;
    r.u[0] = d0; r.u[1] = d1; r.u[2] = d2; r.u[3] = d3; return r.v;
}
static __device__ __forceinline__ uint2v plswap(unsigned a, unsigned b) {
#if __has_builtin(__builtin_amdgcn_permlane32_swap)
    return __builtin_amdgcn_permlane32_swap(a, b, false, false);
#else
    unsigned ax = (unsigned)__shfl_xor((int)a, 32);
    unsigned bx = (unsigned)__shfl_xor((int)b, 32);
    int hi = (threadIdx.x >> 5) & 1;
    uint2v r;
    r.x = hi ? bx : a;
    r.y = hi ? b  : ax;
    return r;
#endif
}
// S~ (K·Q^T) 32x32 C/D block -> exp2 (no shift: cancels in O/l)
// -> two PV B-fragments (16-key slices) + l partials.
static __device__ __forceinline__ void soft_pack(
    const f32x16& s, float& l, bf16x8& f0, bf16x8& f1)
{
    float p[16];
#pragma unroll
    for (int r = 0; r < 16; r++) p[r] = __builtin_amdgcn_exp2f(s[r]);
    float lp = 0.f;
#pragma unroll
    for (int r = 0; r < 16; r++) lp += p[r];
    l += lp;
    unsigned a0 = pack2(p[0],  p[1]),  b0 = pack2(p[2],  p[3]);
    unsigned a1 = pack2(p[4],  p[5]),  b1 = pack2(p[6],  p[7]);
    unsigned a2 = pack2(p[8],  p[9]),  b2 = pack2(p[10], p[11]);
    unsigned a3 = pack2(p[12], p[13]), b3 = pack2(p[14], p[15]);
    uint2v rA0 = plswap(a0, a1), rB0 = plswap(b0, b1);
    uint2v rA1 = plswap(a2, a3), rB1 = plswap(b2, b3);
    f0 = mkfrag(rA0.x, rB0.x, rA0.y, rB0.y);   // keys 0..15
    f1 = mkfrag(rA1.x, rB1.x, rA1.y, rB1.y);   // keys 16..31
}

// ---------------------------------------------------------------------------
// Kernel 2: key-split flash attention, R13 structure verbatim (batched V
// clauses, NO setprio — proven -9% in this lockstep 2-wave structure).
// Wave = 32q x 256ch x 2048 keys; zero softmax redundancy; 2 waves/SIMD;
// merge via bf16 LDS + ONE barrier.
// ---------------------------------------------------------------------------
__global__ __launch_bounds__(256, 2) void k_attn(
    const __bf16* __restrict__ Qt, const __bf16* __restrict__ Kt,
    const __bf16* __restrict__ Vb, const float* __restrict__ x,
    const float* __restrict__ gamma, float* __restrict__ out)
{
    __shared__ __bf16 accs[2][C_DIM][32];   // 32 KiB: ks=1 partial O
    __shared__ float  lbuf[2][32];

    int bid = blockIdx.x;            // 512 blocks, 2 per CU
    int b   = bid & 7;               // batch -> XCD affinity (K/V in 4MB L2)
    int qp  = bid >> 3;              // 0..63 : query-tile pair
    int wid  = threadIdx.x >> 6;
    int qsel = wid >> 1;             // which of the 2 query-tiles
    int ks   = wid & 1;              // key half
    int li  = threadIdx.x & 31;
    int hi  = (threadIdx.x >> 5) & 1;
    int n0q = (qp * 2 + qsel) * 32;

    const __bf16* Qtb = Qt + (size_t)b * (N_DIM * 32);
    const __bf16* Ktb = Kt + (size_t)b * (N_DIM * 32);
    const __bf16* Vtb = Vb + (size_t)b * (N_DIM * C_DIM);

    const __bf16* Qlp = Qtb + ((n0q >> 5) << 10) + (hi << 8) + (li << 3);
    bf16x8 qf0 = *(const bf16x8*)(Qlp);        // d 0-15
    bf16x8 qf1 = *(const bf16x8*)(Qlp + 512);  // d 16-31

    const __bf16* Klp = Ktb + ((size_t)(ks * KSTEPS) << 10) + (hi << 8) + (li << 3);
    const __bf16* Vlp = Vtb + ((size_t)(ks * KSTEPS) << 13) + (hi << 11) + (li << 3);

    f32x16 acc0 = {}, acc1 = {}, acc2 = {}, acc3 = {};
    f32x16 acc4 = {}, acc5 = {}, acc6 = {}, acc7 = {};
    float l0 = 0.f;

    bf16x8 kA0, kA1, kB0, kB1;

#define KLOAD(D0, D1, S)                                                       \
    { const __bf16* Kn = Klp + ((size_t)(S) << 10);                            \
      D0 = *(const bf16x8*)(Kn); D1 = *(const bf16x8*)(Kn + 512); }

    // STEP(I): s = QK(I) from KU; prefetch K(KS2)->KL; V in 2 batched chunks
    // of 8 loads (clause-friendly); PV interleaved with the 2nd chunk.
#define STEP(KU0, KU1, KL0, KL1, KS2, I)                                       \
    {                                                                          \
        f32x16 z = {};                                                         \
        f32x16 s = __builtin_amdgcn_mfma_f32_32x32x16_bf16(KU0, qf0, z, 0, 0, 0); \
        s = __builtin_amdgcn_mfma_f32_32x32x16_bf16(KU1, qf1, s, 0, 0, 0);     \
        KLOAD(KL0, KL1, KS2)                                                   \
        const __bf16* Vn = Vlp + ((size_t)(I) << 13);                          \
        bf16x8 v0 = *(const bf16x8*)(Vn);                                      \
        bf16x8 v1 = *(const bf16x8*)(Vn + 4096);                               \
        bf16x8 v2 = *(const bf16x8*)(Vn + 256);                                \
        bf16x8 v3 = *(const bf16x8*)(Vn + 4096 + 256);                         \
        bf16x8 v4 = *(const bf16x8*)(Vn + 512);                                \
        bf16x8 v5 = *(const bf16x8*)(Vn + 4096 + 512);                         \
        bf16x8 v6 = *(const bf16x8*)(Vn + 768);                                \
        bf16x8 v7 = *(const bf16x8*)(Vn + 4096 + 768);                         \
        bf16x8 p0, p1;                                                         \
        soft_pack(s, l0, p0, p1);                                              \
        acc0 = __builtin_amdgcn_mfma_f32_32x32x16_bf16(v0, p0, acc0, 0, 0, 0); \
        acc0 = __builtin_amdgcn_mfma_f32_32x32x16_bf16(v1, p1, acc0, 0, 0, 0); \
        bf16x8 w0 = *(const bf16x8*)(Vn + 1024);                               \
        bf16x8 w1 = *(const bf16x8*)(Vn + 4096 + 1024);                        \
        acc1 = __builtin_amdgcn_mfma_f32_32x32x16_bf16(v2, p0, acc1, 0, 0, 0); \
        acc1 = __builtin_amdgcn_mfma_f32_32x32x16_bf16(v3, p1, acc1, 0, 0, 0); \
        bf16x8 w2 = *(const bf16x8*)(Vn + 1280);                               \
        bf16x8 w3 = *(const bf16x8*)(Vn + 4096 + 1280);                        \
        acc2 = __builtin_amdgcn_mfma_f32_32x32x16_bf16(v4, p0, acc2, 0, 0, 0); \
        acc2 = __builtin_amdgcn_mfma_f32_32x32x16_bf16(v5, p1, acc2, 0, 0, 0); \
        bf16x8 w4 = *(const bf16x8*)(Vn + 1536);                               \
        bf16x8 w5 = *(const bf16x8*)(Vn + 4096 + 1536);                        \
        acc3 = __builtin_amdgcn_mfma_f32_32x32x16_bf16(v6, p0, acc3, 0, 0, 0); \
        acc3 = __builtin_amdgcn_mfma_f32_32x32x16_bf16(v7, p1, acc3, 0, 0, 0); \
        bf16x8 w6 = *(const bf16x8*)(Vn + 1792);                               \
        bf16x8 w7 = *(const bf16x8*)(Vn + 4096 + 1792);                        \
        acc4 = __builtin_amdgcn_mfma_f32_32x32x16_bf16(w0, p0, acc4, 0, 0, 0); \
        acc4 = __builtin_amdgcn_mfma_f32_32x32x16_bf16(w1, p1, acc4, 0, 0, 0); \
        acc5 = __builtin_amdgcn_mfma_f32_32x32x16_bf16(w2, p0, acc5, 0, 0, 0); \
        acc5 = __builtin_amdgcn_mfma_f32_32x32x16_bf16(w3, p1, acc5, 0, 0, 0); \
        acc6 = __builtin_amdgcn_mfma_f32_32x32x16_bf16(w4, p0, acc6, 0, 0, 0); \
        acc6 = __builtin_amdgcn_mfma_f32_32x32x16_bf16(w5, p1, acc6, 0, 0, 0); \
        acc7 = __builtin_amdgcn_mfma_f32_32x32x16_bf16(w6, p0, acc7, 0, 0, 0); \
        acc7 = __builtin_amdgcn_mfma_f32_32x32x16_bf16(w7, p1, acc7, 0, 0, 0); \
    }

    // prologue: K(0), K(1)
    KLOAD(kA0, kA1, 0)
    KLOAD(kB0, kB1, 1)

    for (int i = 0; i < KSTEPS - 2; i += 2) {
        STEP(kA0, kA1, kA0, kA1, i + 2, i)
        STEP(kB0, kB1, kB0, kB1, i + 3, i + 1)
    }
    STEP(kA0, kA1, kA0, kA1, KSTEPS - 1, KSTEPS - 2)   // K reload: harmless
    STEP(kB0, kB1, kB0, kB1, KSTEPS - 1, KSTEPS - 1)

#undef STEP
#undef KLOAD

    // ---- merge the two key halves: ks=1 -> LDS (bf16 partials + l), barrier,
    //      ks=0 adds and runs the fused epilogue.
    float lv = l0 + __shfl_xor(l0, 32);   // per-lane query li's partial sum

    if (ks == 1) {
        if (hi == 0) lbuf[qsel][li] = lv;
#define SPILL_ACC(A, G)                                                        \
        _Pragma("unroll")                                                      \
        for (int rg = 0; rg < 16; rg++) {                                      \
            int row = (rg & 3) + 8 * (rg >> 2) + 4 * hi;                       \
            accs[qsel][(G) * 32 + row][li] = (__bf16)A[rg];                    \
        }
        SPILL_ACC(acc0, 0) SPILL_ACC(acc1, 1) SPILL_ACC(acc2, 2) SPILL_ACC(acc3, 3)
        SPILL_ACC(acc4, 4) SPILL_ACC(acc5, 5) SPILL_ACC(acc6, 6) SPILL_ACC(acc7, 7)
#undef SPILL_ACC
    }
    __syncthreads();
    if (ks == 0) {
        float lt = lv + lbuf[qsel][li];
        float linv = gamma[0] / lt;
#define STORE_ACC(A, G)                                                        \
        _Pragma("unroll")                                                      \
        for (int rg = 0; rg < 16; rg++) {                                      \
            int row = (rg & 3) + 8 * (rg >> 2) + 4 * hi;                       \
            int c = (G) * 32 + row;                                            \
            size_t idx = ((size_t)b * C_DIM + c) * N_DIM + (n0q + li);         \
            float o = A[rg] + (float)accs[qsel][c][li];                        \
            out[idx] = o * linv + x[idx];                                      \
        }
        STORE_ACC(acc0, 0) STORE_ACC(acc1, 1) STORE_ACC(acc2, 2) STORE_ACC(acc3, 3)
        STORE_ACC(acc4, 4) STORE_ACC(acc5, 5) STORE_ACC(acc6, 6) STORE_ACC(acc7, 7)
#undef STORE_ACC
    }
}

// ---------------------------------------------------------------------------
extern "C" void kernel_launch(void* const* d_in, const int* in_sizes, int n_in,
                              void* d_out, int out_size, void* d_ws, size_t ws_size,
                              hipStream_t stream)
{
    const float* x     = (const float*)d_in[0];
    const float* Wq    = (const float*)d_in[1];
    const float* bq    = (const float*)d_in[2];
    const float* Wk    = (const float*)d_in[3];
    const float* bk    = (const float*)d_in[4];
    const float* Wv    = (const float*)d_in[5];
    const float* bv    = (const float*)d_in[6];
    const float* gamma = (const float*)d_in[7];
    float* out = (float*)d_out;

    char* ws = (char*)d_ws;
    const size_t MB = 1024 * 1024;
    __bf16* Qt = (__bf16*)ws;                      //  2 MiB (tiled)
    __bf16* Kt = (__bf16*)(ws + 2 * MB);           //  2 MiB (tiled)
    __bf16* Vb = (__bf16*)(ws + 4 * MB);           // 16 MiB (tiled)

    k_qkv<<<512, 256, 0, stream>>>(x, Wq, bq, Wk, bk, Wv, bv, Qt, Kt, Vb);
    k_attn<<<512, 256, 0, stream>>>(Qt, Kt, Vb, x, gamma, out);
}